// Round 7
// baseline (194.709 us; speedup 1.0000x reference)
//
#include <hip/hip_runtime.h>
#include <hip/hip_bf16.h>

typedef __attribute__((ext_vector_type(8))) short short8;
typedef __attribute__((ext_vector_type(4))) float f32x4;

#define HEADS 16
#define DH    64
#define LSEQ  512
#define CD    1024
#define MROWS 8192            /* B*T*L */

static __device__ __forceinline__ unsigned short f2bf(float f) {
    union { float f; unsigned int u; } v; v.f = f;
    unsigned int u = v.u;
    u += 0x7fffu + ((u >> 16) & 1u);   // round-to-nearest-even
    return (unsigned short)(u >> 16);
}

static __device__ __forceinline__ void gload16(const unsigned short* g, char* lds) {
    __builtin_amdgcn_global_load_lds(
        (const __attribute__((address_space(1))) void*)g,
        (__attribute__((address_space(3))) void*)lds, 16, 0, 0);
}

// ---------------- f32 -> bf16 bulk convert (vec4) ----------------
__global__ __launch_bounds__(256)
void cvt_kernel(const float* __restrict__ s, unsigned short* __restrict__ d, int n4) {
    union U { unsigned short us[4]; unsigned long long u; };
    for (int i = blockIdx.x * blockDim.x + threadIdx.x; i < n4; i += gridDim.x * blockDim.x) {
        const float4 v = ((const float4*)s)[i];
        U p; p.us[0] = f2bf(v.x); p.us[1] = f2bf(v.y); p.us[2] = f2bf(v.z); p.us[3] = f2bf(v.w);
        ((unsigned long long*)d)[i] = p.u;
    }
}

// ================= 2-phase double-buffered GEMM core (T3 minimum recipe) ====
// BM=BN=128, BK=64, 4 waves (2x2), 2x32KB LDS dbuf, ONE raw barrier per K-tile.
// Per K-tile: ds_read cur || stage(next) -> lgkmcnt(0) -> MFMA -> vmcnt(0) ->
// s_barrier. Stage issued BEFORE compute so HBM/L2 latency hides under MFMA.
// T2 both-sides XOR chunk swizzle; 2 blocks/CU co-resident for drain overlap.
static __device__ __forceinline__ void gemm128_core(
    const unsigned short* __restrict__ Ap,   // [M][CD] bf16, row-major
    const unsigned short* __restrict__ Bp,   // [N][CD] bf16, row-major
    int i0, int n0, char* lds, f32x4 acc[4][4])
{
    const int tid  = threadIdx.x;
    const int wv   = tid >> 6;        // 0..3
    const int lane = tid & 63;
    const int colw = lane & 15;
    const int grp  = lane >> 4;
    const int wr   = wv >> 1;         // row half
    const int wc   = wv & 1;          // col half

    // staging: per instr, wave covers 8 rows x 128B (dense); LDS dest linear.
    // global chunk pre-swizzled so LDS phys chunk p holds logical p^(row&7).
    const int srow0 = lane >> 3;                 // 0..7 row within 8-row chunk
    const int sclog = (lane & 7) ^ (srow0 & 7);  // row&7 == srow0&7 for +8-multiples
    const int adst  = wv * 32 * 128;             // byte offsets within buf
    const int bdst  = 32768 + wv * 32 * 128;

    // ds_read byte offsets (swizzled): row*128 + ((ks*4+grp)^(row&7))*16
    int aoff[2][4], boff[2][4];
    #pragma unroll
    for (int ks = 0; ks < 2; ++ks) {
        #pragma unroll
        for (int f = 0; f < 4; ++f) {
            const int ra = wr * 64 + f * 16 + colw;
            const int rb = wc * 64 + f * 16 + colw;
            aoff[ks][f] = ra * 128 + (((ks * 4 + grp) ^ (ra & 7)) << 4);
            boff[ks][f] = 32768 + rb * 128 + (((ks * 4 + grp) ^ (rb & 7)) << 4);
        }
    }

    const int NT = CD / 64;   // 16 K-tiles

    // ---- prologue: stage tile 0 into buf0, full drain once ----
    #pragma unroll
    for (int c = 0; c < 4; ++c) {
        const int row = wv * 32 + c * 8 + srow0;
        gload16(Ap + (size_t)(i0 + row) * CD + sclog * 8, lds + adst + c * 1024);
        gload16(Bp + (size_t)(n0 + row) * CD + sclog * 8, lds + bdst + c * 1024);
    }
    asm volatile("s_waitcnt vmcnt(0)" ::: "memory");
    __builtin_amdgcn_sched_barrier(0);
    __builtin_amdgcn_s_barrier();

    for (int t = 0; t < NT; ++t) {
        char* const cb = lds + (t & 1) * 65536;         // current buf (ready)
        char* const nb = lds + ((t & 1) ^ 1) * 65536;   // next buf (staging)

        // issue ds_reads of current tile
        short8 af[2][4], bf[2][4];
        #pragma unroll
        for (int ks = 0; ks < 2; ++ks) {
            #pragma unroll
            for (int f = 0; f < 4; ++f) {
                af[ks][f] = *(const short8*)(cb + aoff[ks][f]);
                bf[ks][f] = *(const short8*)(cb + boff[ks][f]);
            }
        }
        // issue next-tile stage EARLY (hides under ds_read latency + MFMA)
        if (t + 1 < NT) {
            const int kt = (t + 1) * 64;
            #pragma unroll
            for (int c = 0; c < 4; ++c) {
                const int row = wv * 32 + c * 8 + srow0;
                gload16(Ap + (size_t)(i0 + row) * CD + kt + sclog * 8, nb + adst + c * 1024);
                gload16(Bp + (size_t)(n0 + row) * CD + kt + sclog * 8, nb + bdst + c * 1024);
            }
        }
        asm volatile("s_waitcnt lgkmcnt(0)" ::: "memory");
        __builtin_amdgcn_sched_barrier(0);

        __builtin_amdgcn_s_setprio(1);
        #pragma unroll
        for (int ks = 0; ks < 2; ++ks)
            #pragma unroll
            for (int mf = 0; mf < 4; ++mf)
                #pragma unroll
                for (int nf = 0; nf < 4; ++nf)
                    acc[mf][nf] = __builtin_amdgcn_mfma_f32_16x16x32_bf16(af[ks][mf], bf[ks][nf], acc[mf][nf], 0, 0, 0);
        __builtin_amdgcn_s_setprio(0);

        // gate: next buf fully landed; all waves past lgkmcnt (reads done)
        asm volatile("s_waitcnt vmcnt(0)" ::: "memory");
        __builtin_amdgcn_sched_barrier(0);
        __builtin_amdgcn_s_barrier();
    }
}

// ---------------- Kernel 1: fused QKV projection ----------
__global__ __launch_bounds__(256, 2)
void proj_qkv_kernel(const unsigned short* __restrict__ xb,
                     const unsigned short* __restrict__ wqkvb,
                     const float* __restrict__ bq, const float* __restrict__ bkv,
                     unsigned short* __restrict__ Qb, unsigned short* __restrict__ Kb,
                     unsigned short* __restrict__ Vtb)
{
    __shared__ __attribute__((aligned(16))) char lds[128 * 1024];

    // grid = 1536 (64 m x 24 n); bijective XCD swizzle; m-chunk per XCD
    const int xcd = blockIdx.x & 7, wgl = blockIdx.x >> 3;   // wgl 0..191
    const int im  = xcd * 8 + wgl / 24;
    const int in  = wgl % 24;
    const int i0 = im * 128, j0 = in * 128;

    const int tid  = threadIdx.x;
    const int wv   = tid >> 6;
    const int lane = tid & 63;
    const int colw = lane & 15;
    const int grp  = lane >> 4;
    const int wr   = wv >> 1, wc = wv & 1;

    f32x4 acc[4][4] = {};
    gemm128_core(xb, wqkvb, i0, j0, lds, acc);

    // ---- epilogue: bias + l2norm over 64-col head; scatter store ----
    const int jbase = j0 + wc * 64;               // head-aligned, wave-uniform
    const float* bp = (jbase < CD) ? (bq + jbase) : (bkv + (jbase - CD));
    #pragma unroll
    for (int nf = 0; nf < 4; ++nf) {
        const float bv = bp[nf * 16 + colw];
        #pragma unroll
        for (int mf = 0; mf < 4; ++mf)
            #pragma unroll
            for (int r = 0; r < 4; ++r) acc[mf][nf][r] += bv;
    }
    const float qscale = (jbase < CD) ? 0.125f : 1.0f;
    float inv[4][4];
    #pragma unroll
    for (int mf = 0; mf < 4; ++mf) {
        #pragma unroll
        for (int r = 0; r < 4; ++r) {
            float t = 0.f;
            #pragma unroll
            for (int nf = 0; nf < 4; ++nf) t += acc[mf][nf][r] * acc[mf][nf][r];
            t += __shfl_xor(t, 1);
            t += __shfl_xor(t, 2);
            t += __shfl_xor(t, 4);
            t += __shfl_xor(t, 8);
            inv[mf][r] = qscale / fmaxf(sqrtf(t), 1e-12f);
        }
    }
    // wave-uniform destination select
    unsigned short* dst; int jloc;
    if (jbase < CD)            { dst = Qb;  jloc = jbase; }
    else if (jbase < 2 * CD)   { dst = Kb;  jloc = jbase - CD; }
    else                       { dst = Vtb; jloc = jbase - 2 * CD; }
    const int h = jloc >> 6;
    #pragma unroll
    for (int mf = 0; mf < 4; ++mf) {
        #pragma unroll
        for (int nf = 0; nf < 4; ++nf) {
            const int d = nf * 16 + colw;
            #pragma unroll
            for (int r = 0; r < 4; ++r) {
                const int i  = i0 + wr * 64 + mf * 16 + grp * 4 + r;
                const int bt = i >> 9, li = i & 511;
                const unsigned short hv = f2bf(acc[mf][nf][r] * inv[mf][r]);
                if (jbase < 2 * CD)
                    dst[(((size_t)(bt * HEADS + h)) * LSEQ + li) * DH + d] = hv;     // Q or K [l][d]
                else
                    // V tiled: [bth][l/64][d][64] -> contiguous 8KB kv-tiles for attn
                    dst[((((size_t)(bt * HEADS + h)) * 8 + (li >> 6)) * DH + d) * 64 + (li & 63)] = hv;
            }
        }
    }
}

// ---------------- Kernel 2: flash attention per (b,t,h) ----------
// Bounded-score softmax (|s|<=0.125): exp(s) directly, no max tracking.
// 8 waves x 16 q-rows = 128 q/block; K/V kv-tiles (64x64, contiguous 8KB)
// staged in LDS once per block via global_load_lds, XOR-swizzled both sides.
__global__ __launch_bounds__(512)
void attn_kernel(const unsigned short* __restrict__ Qb,
                 const unsigned short* __restrict__ Kb,
                 const unsigned short* __restrict__ Vtb,   // tiled [bth][8][64][64]
                 unsigned short* __restrict__ Ob)
{
    __shared__ __attribute__((aligned(16))) unsigned short Ksm[64 * 64];
    __shared__ __attribute__((aligned(16))) unsigned short Vsm[64 * 64];
    __shared__ __attribute__((aligned(16))) unsigned short Psm[8][16 * 72];

    const int tid  = threadIdx.x;
    const int w    = tid >> 6;        // 0..7
    const int lane = tid & 63;
    const int colw = lane & 15;
    const int grp  = lane >> 4;

    const int bth = blockIdx.x & 255;     // head id (same XCD for all its q-tiles)
    const int qt  = blockIdx.x >> 8;      // 0..3
    const int q0  = qt * 128 + w * 16;    // wave's first q row

    const unsigned short* Qh = Qb  + (size_t)bth * LSEQ * DH;
    const unsigned short* Kh = Kb  + (size_t)bth * LSEQ * DH;
    const unsigned short* Vh = Vtb + (size_t)bth * LSEQ * DH;  // tiled

    short8 aq[2];
    #pragma unroll
    for (int ks = 0; ks < 2; ++ks)
        aq[ks] = *(const short8*)&Qh[(size_t)(q0 + colw) * DH + ks * 32 + grp * 8];

    // staging source (pre-swizzled): LDS linear dest = wave base + lane*16
    const int srow   = w * 8 + (lane >> 3);          // 0..63
    const int schunk = (lane & 7) ^ (srow & 7);      // swizzled 16B chunk
    const int goff   = srow * DH + schunk * 8;       // element offset in 8KB tile
    char* const kdst = (char*)Ksm + w * 1024;
    char* const vdst = (char*)Vsm + w * 1024;

    float plsum[4] = {0.f, 0.f, 0.f, 0.f};
    f32x4 oacc[4] = {};

    for (int t = 0; t < 8; ++t) {
        gload16(Kh + t * 4096 + goff, kdst);
        gload16(Vh + t * 4096 + goff, vdst);
        __syncthreads();                 // drains vmcnt -> tiles ready

        // ---- QK^T: s[nf] covers kv cols nf*16+colw, q rows grp*4+r ----
        f32x4 s[4] = {};
        #pragma unroll
        for (int ks = 0; ks < 2; ++ks) {
            #pragma unroll
            for (int nf = 0; nf < 4; ++nf) {
                const int rowb = nf * 16 + colw;
                const short8 bk = *(const short8*)((char*)Ksm + rowb * 128 +
                                       ((((ks * 4 + grp) ^ (rowb & 7))) << 4));
                s[nf] = __builtin_amdgcn_mfma_f32_16x16x32_bf16(aq[ks], bk, s[nf], 0, 0, 0);
            }
        }
        // ---- p = exp(s), accumulate row sums, write P to per-wave LDS ----
        #pragma unroll
        for (int nf = 0; nf < 4; ++nf) {
            #pragma unroll
            for (int r = 0; r < 4; ++r) {
                const float p = __expf(s[nf][r]);
                plsum[r] += p;
                Psm[w][(grp * 4 + r) * 72 + nf * 16 + colw] = f2bf(p);
            }
        }
        // ---- PV: A = P (k=kv), B = V_lds (rows=d, k=kv) ----
        #pragma unroll
        for (int ks2 = 0; ks2 < 2; ++ks2) {
            const short8 ap = *(const short8*)&Psm[w][colw * 72 + ks2 * 32 + grp * 8];
            #pragma unroll
            for (int nf = 0; nf < 4; ++nf) {
                const int rowv = nf * 16 + colw;
                const short8 bv = *(const short8*)((char*)Vsm + rowv * 128 +
                                       ((((ks2 * 4 + grp) ^ (rowv & 7))) << 4));
                oacc[nf] = __builtin_amdgcn_mfma_f32_16x16x32_bf16(ap, bv, oacc[nf], 0, 0, 0);
            }
        }
        __syncthreads();                 // protect LDS tiles before restage
    }

    // single cross-lane reduce of the row sums (16-lane groups)
    float oinv[4];
    #pragma unroll
    for (int r = 0; r < 4; ++r) {
        float t = plsum[r];
        t += __shfl_xor(t, 1);
        t += __shfl_xor(t, 2);
        t += __shfl_xor(t, 4);
        t += __shfl_xor(t, 8);
        oinv[r] = 1.0f / t;
    }

    const int bt = bth >> 4, h = bth & 15;
    #pragma unroll
    for (int nf = 0; nf < 4; ++nf) {
        #pragma unroll
        for (int r = 0; r < 4; ++r) {
            const int i = bt * LSEQ + q0 + grp * 4 + r;
            const int c = h * 64 + nf * 16 + colw;
            Ob[(size_t)i * CD + c] = f2bf(oacc[nf][r] * oinv[r]);
        }
    }
}

// ---------------- Kernel 3: output projection + bias + residual ----------
__global__ __launch_bounds__(256, 2)
void proj_out_kernel(const unsigned short* __restrict__ Ob,
                     const unsigned short* __restrict__ wmb,
                     const float* __restrict__ bm,
                     const float* __restrict__ x, float* __restrict__ out)
{
    __shared__ __attribute__((aligned(16))) char lds[128 * 1024];

    // grid = 512 (64 m x 8 n); bijective XCD swizzle
    const int xcd = blockIdx.x & 7, wgl = blockIdx.x >> 3;   // wgl 0..63
    const int im  = xcd * 8 + (wgl >> 3);
    const int in  = wgl & 7;
    const int i0 = im * 128, j0 = in * 128;

    const int tid  = threadIdx.x;
    const int wv   = tid >> 6;
    const int lane = tid & 63;
    const int colw = lane & 15;
    const int grp  = lane >> 4;
    const int wr   = wv >> 1, wc = wv & 1;

    f32x4 acc[4][4] = {};
    gemm128_core(Ob, wmb, i0, j0, lds, acc);

    #pragma unroll
    for (int nf = 0; nf < 4; ++nf) {
        const int j = j0 + wc * 64 + nf * 16 + colw;
        const float bv = bm[j];
        #pragma unroll
        for (int mf = 0; mf < 4; ++mf) {
            #pragma unroll
            for (int r = 0; r < 4; ++r) {
                const int i = i0 + wr * 64 + mf * 16 + grp * 4 + r;
                out[(size_t)i * CD + j] = acc[mf][nf][r] + bv + x[(size_t)i * CD + j];
            }
        }
    }
}

extern "C" void kernel_launch(void* const* d_in, const int* in_sizes, int n_in,
                              void* d_out, int out_size, void* d_ws, size_t ws_size,
                              hipStream_t stream) {
    const float* x   = (const float*)d_in[0];
    const float* wq  = (const float*)d_in[1];
    const float* bq  = (const float*)d_in[2];
    const float* wkv = (const float*)d_in[3];
    const float* bkv = (const float*)d_in[4];
    const float* wm  = (const float*)d_in[5];
    const float* bm  = (const float*)d_in[6];
    float* out = (float*)d_out;

    // ws layout (64 MB, timeline-aliased):
    //  R0: xb (convert->proj_qkv), then Ob (attn->proj_out)
    //  R1: Qb (proj_qkv->attn), then wmb (cvt-after-attn->proj_out)
    //  R2: Kb   R3: Vtb
    // wqkvb lives in d_out (dead before proj_out writes it).
    const size_t SEG = (size_t)MROWS * CD;
    unsigned short* xb    = (unsigned short*)d_ws;
    unsigned short* Ob    = xb;
    unsigned short* Qb    = xb + SEG;
    unsigned short* wmb   = Qb;
    unsigned short* Kb    = Qb + SEG;
    unsigned short* Vtb   = Kb + SEG;
    unsigned short* wqkvb = (unsigned short*)d_out;

    cvt_kernel<<<2048, 256, 0, stream>>>(x,   xb,    (MROWS * CD) / 4);
    cvt_kernel<<<1024, 256, 0, stream>>>(wq,  wqkvb, (CD * CD) / 4);
    cvt_kernel<<<1024, 256, 0, stream>>>(wkv, wqkvb + (size_t)CD * CD, (2 * CD * CD) / 4);
    proj_qkv_kernel<<<1536, 256, 0, stream>>>(xb, wqkvb, bq, bkv, Qb, Kb, Vtb);
    attn_kernel<<<1024, 512, 0, stream>>>(Qb, Kb, Vtb, Ob);
    cvt_kernel<<<1024, 256, 0, stream>>>(wm, wmb, (CD * CD) / 4);
    proj_out_kernel<<<512, 256, 0, stream>>>(Ob, wmb, bm, x, out);
}

// Round 8
// 153.387 us; speedup vs baseline: 1.2694x; 1.2694x over previous
//
#include <hip/hip_runtime.h>
#include <hip/hip_bf16.h>

typedef __attribute__((ext_vector_type(8))) short short8;
typedef __attribute__((ext_vector_type(4))) float f32x4;

#define HEADS 16
#define DH    64
#define LSEQ  512
#define CD    1024
#define MROWS 8192            /* B*T*L */

static __device__ __forceinline__ unsigned short f2bf(float f) {
    union { float f; unsigned int u; } v; v.f = f;
    unsigned int u = v.u;
    u += 0x7fffu + ((u >> 16) & 1u);   // round-to-nearest-even
    return (unsigned short)(u >> 16);
}

static __device__ __forceinline__ void gload16(const unsigned short* g, char* lds) {
    __builtin_amdgcn_global_load_lds(
        (const __attribute__((address_space(1))) void*)g,
        (__attribute__((address_space(3))) void*)lds, 16, 0, 0);
}

// ---------------- f32 -> bf16 bulk convert (vec4) ----------------
__global__ __launch_bounds__(256)
void cvt_kernel(const float* __restrict__ s, unsigned short* __restrict__ d, int n4) {
    union U { unsigned short us[4]; unsigned long long u; };
    for (int i = blockIdx.x * blockDim.x + threadIdx.x; i < n4; i += gridDim.x * blockDim.x) {
        const float4 v = ((const float4*)s)[i];
        U p; p.us[0] = f2bf(v.x); p.us[1] = f2bf(v.y); p.us[2] = f2bf(v.z); p.us[3] = f2bf(v.w);
        ((unsigned long long*)d)[i] = p.u;
    }
}

// ================= 2-phase double-buffered GEMM core (T3 minimum recipe) ====
// BM=BN=128, BK=64, 4 waves (2x2), 2 x 32KB LDS dbuf (64KB total -> 2 blk/CU),
// ONE raw barrier per K-tile. Per K-tile: ds_read cur || stage(next) ->
// lgkmcnt(0) -> MFMA -> vmcnt(0) -> s_barrier. Stage issued BEFORE compute so
// load latency hides under MFMA; residual drain hides under the co-resident
// block (m114 mechanism). T2 both-sides XOR chunk swizzle.
#define BUFB 32768   /* bytes per LDS buffer: A 16KB + B 16KB */

static __device__ __forceinline__ void gemm128_core(
    const unsigned short* __restrict__ Ap,   // [M][CD] bf16, row-major
    const unsigned short* __restrict__ Bp,   // [N][CD] bf16, row-major
    int i0, int n0, char* lds, f32x4 acc[4][4])
{
    const int tid  = threadIdx.x;
    const int wv   = tid >> 6;        // 0..3
    const int lane = tid & 63;
    const int colw = lane & 15;
    const int grp  = lane >> 4;
    const int wr   = wv >> 1;         // row half
    const int wc   = wv & 1;          // col half

    // staging: per instr, wave covers 8 rows x 128B (dense); LDS dest linear.
    // global chunk pre-swizzled so LDS phys chunk p holds logical p^(row&7).
    const int srow0 = lane >> 3;                 // 0..7 row within 8-row chunk
    const int sclog = (lane & 7) ^ (srow0 & 7);  // row&7 == srow0&7 for +8-multiples
    const int adst  = wv * 32 * 128;             // byte offsets within buf (A: 0..16K)
    const int bdst  = 16384 + wv * 32 * 128;     // B: 16K..32K

    // ds_read byte offsets (swizzled): row*128 + ((ks*4+grp)^(row&7))*16
    int aoff[2][4], boff[2][4];
    #pragma unroll
    for (int ks = 0; ks < 2; ++ks) {
        #pragma unroll
        for (int f = 0; f < 4; ++f) {
            const int ra = wr * 64 + f * 16 + colw;
            const int rb = wc * 64 + f * 16 + colw;
            aoff[ks][f] = ra * 128 + (((ks * 4 + grp) ^ (ra & 7)) << 4);
            boff[ks][f] = 16384 + rb * 128 + (((ks * 4 + grp) ^ (rb & 7)) << 4);
        }
    }

    const int NT = CD / 64;   // 16 K-tiles

    // ---- prologue: stage tile 0 into buf0, full drain once ----
    #pragma unroll
    for (int c = 0; c < 4; ++c) {
        const int row = wv * 32 + c * 8 + srow0;
        gload16(Ap + (size_t)(i0 + row) * CD + sclog * 8, lds + adst + c * 1024);
        gload16(Bp + (size_t)(n0 + row) * CD + sclog * 8, lds + bdst + c * 1024);
    }
    asm volatile("s_waitcnt vmcnt(0)" ::: "memory");
    __builtin_amdgcn_sched_barrier(0);
    __builtin_amdgcn_s_barrier();

    for (int t = 0; t < NT; ++t) {
        char* const cb = lds + (t & 1) * BUFB;          // current buf (ready)
        char* const nb = lds + ((t & 1) ^ 1) * BUFB;    // next buf (staging)

        // issue ds_reads of current tile
        short8 af[2][4], bf[2][4];
        #pragma unroll
        for (int ks = 0; ks < 2; ++ks) {
            #pragma unroll
            for (int f = 0; f < 4; ++f) {
                af[ks][f] = *(const short8*)(cb + aoff[ks][f]);
                bf[ks][f] = *(const short8*)(cb + boff[ks][f]);
            }
        }
        // issue next-tile stage EARLY (hides under ds_read latency + MFMA)
        if (t + 1 < NT) {
            const int kt = (t + 1) * 64;
            #pragma unroll
            for (int c = 0; c < 4; ++c) {
                const int row = wv * 32 + c * 8 + srow0;
                gload16(Ap + (size_t)(i0 + row) * CD + kt + sclog * 8, nb + adst + c * 1024);
                gload16(Bp + (size_t)(n0 + row) * CD + kt + sclog * 8, nb + bdst + c * 1024);
            }
        }
        asm volatile("s_waitcnt lgkmcnt(0)" ::: "memory");
        __builtin_amdgcn_sched_barrier(0);

        __builtin_amdgcn_s_setprio(1);
        #pragma unroll
        for (int ks = 0; ks < 2; ++ks)
            #pragma unroll
            for (int mf = 0; mf < 4; ++mf)
                #pragma unroll
                for (int nf = 0; nf < 4; ++nf)
                    acc[mf][nf] = __builtin_amdgcn_mfma_f32_16x16x32_bf16(af[ks][mf], bf[ks][nf], acc[mf][nf], 0, 0, 0);
        __builtin_amdgcn_s_setprio(0);

        // gate: next buf fully landed; all waves past lgkmcnt (reads done)
        asm volatile("s_waitcnt vmcnt(0)" ::: "memory");
        __builtin_amdgcn_sched_barrier(0);
        __builtin_amdgcn_s_barrier();
    }
}

// ---------------- Kernel 1: fused QKV projection ----------
__global__ __launch_bounds__(256, 2)
void proj_qkv_kernel(const unsigned short* __restrict__ xb,
                     const unsigned short* __restrict__ wqkvb,
                     const float* __restrict__ bq, const float* __restrict__ bkv,
                     unsigned short* __restrict__ Qb, unsigned short* __restrict__ Kb,
                     unsigned short* __restrict__ Vtb)
{
    __shared__ __attribute__((aligned(16))) char lds[64 * 1024];

    // grid = 1536 (64 m x 24 n); bijective XCD swizzle; m-chunk per XCD
    const int xcd = blockIdx.x & 7, wgl = blockIdx.x >> 3;   // wgl 0..191
    const int im  = xcd * 8 + wgl / 24;
    const int in  = wgl % 24;
    const int i0 = im * 128, j0 = in * 128;

    const int tid  = threadIdx.x;
    const int wv   = tid >> 6;
    const int lane = tid & 63;
    const int colw = lane & 15;
    const int grp  = lane >> 4;
    const int wr   = wv >> 1, wc = wv & 1;

    f32x4 acc[4][4] = {};
    gemm128_core(xb, wqkvb, i0, j0, lds, acc);

    // ---- epilogue: bias + l2norm over 64-col head; scatter store ----
    const int jbase = j0 + wc * 64;               // head-aligned, wave-uniform
    const float* bp = (jbase < CD) ? (bq + jbase) : (bkv + (jbase - CD));
    #pragma unroll
    for (int nf = 0; nf < 4; ++nf) {
        const float bv = bp[nf * 16 + colw];
        #pragma unroll
        for (int mf = 0; mf < 4; ++mf)
            #pragma unroll
            for (int r = 0; r < 4; ++r) acc[mf][nf][r] += bv;
    }
    const float qscale = (jbase < CD) ? 0.125f : 1.0f;
    float inv[4][4];
    #pragma unroll
    for (int mf = 0; mf < 4; ++mf) {
        #pragma unroll
        for (int r = 0; r < 4; ++r) {
            float t = 0.f;
            #pragma unroll
            for (int nf = 0; nf < 4; ++nf) t += acc[mf][nf][r] * acc[mf][nf][r];
            t += __shfl_xor(t, 1);
            t += __shfl_xor(t, 2);
            t += __shfl_xor(t, 4);
            t += __shfl_xor(t, 8);
            inv[mf][r] = qscale / fmaxf(sqrtf(t), 1e-12f);
        }
    }
    // wave-uniform destination select
    unsigned short* dst; int jloc;
    if (jbase < CD)            { dst = Qb;  jloc = jbase; }
    else if (jbase < 2 * CD)   { dst = Kb;  jloc = jbase - CD; }
    else                       { dst = Vtb; jloc = jbase - 2 * CD; }
    const int h = jloc >> 6;
    #pragma unroll
    for (int mf = 0; mf < 4; ++mf) {
        #pragma unroll
        for (int nf = 0; nf < 4; ++nf) {
            const int d = nf * 16 + colw;
            #pragma unroll
            for (int r = 0; r < 4; ++r) {
                const int i  = i0 + wr * 64 + mf * 16 + grp * 4 + r;
                const int bt = i >> 9, li = i & 511;
                const unsigned short hv = f2bf(acc[mf][nf][r] * inv[mf][r]);
                if (jbase < 2 * CD)
                    dst[(((size_t)(bt * HEADS + h)) * LSEQ + li) * DH + d] = hv;     // Q or K [l][d]
                else
                    // V tiled: [bth][l/64][d][64] -> contiguous 8KB kv-tiles for attn
                    dst[((((size_t)(bt * HEADS + h)) * 8 + (li >> 6)) * DH + d) * 64 + (li & 63)] = hv;
            }
        }
    }
}

// ---------------- Kernel 2: flash attention per (b,t,h) ----------
// Bounded-score softmax (|s|<=0.125): exp(s) directly, no max tracking.
// 8 waves x 16 q-rows = 128 q/block; K/V kv-tiles (64x64, contiguous 8KB)
// staged in LDS once per block via global_load_lds, XOR-swizzled both sides.
__global__ __launch_bounds__(512)
void attn_kernel(const unsigned short* __restrict__ Qb,
                 const unsigned short* __restrict__ Kb,
                 const unsigned short* __restrict__ Vtb,   // tiled [bth][8][64][64]
                 unsigned short* __restrict__ Ob)
{
    __shared__ __attribute__((aligned(16))) unsigned short Ksm[64 * 64];
    __shared__ __attribute__((aligned(16))) unsigned short Vsm[64 * 64];
    __shared__ __attribute__((aligned(16))) unsigned short Psm[8][16 * 72];

    const int tid  = threadIdx.x;
    const int w    = tid >> 6;        // 0..7
    const int lane = tid & 63;
    const int colw = lane & 15;
    const int grp  = lane >> 4;

    const int bth = blockIdx.x & 255;     // head id (same XCD for all its q-tiles)
    const int qt  = blockIdx.x >> 8;      // 0..3
    const int q0  = qt * 128 + w * 16;    // wave's first q row

    const unsigned short* Qh = Qb  + (size_t)bth * LSEQ * DH;
    const unsigned short* Kh = Kb  + (size_t)bth * LSEQ * DH;
    const unsigned short* Vh = Vtb + (size_t)bth * LSEQ * DH;  // tiled

    short8 aq[2];
    #pragma unroll
    for (int ks = 0; ks < 2; ++ks)
        aq[ks] = *(const short8*)&Qh[(size_t)(q0 + colw) * DH + ks * 32 + grp * 8];

    // staging source (pre-swizzled): LDS linear dest = wave base + lane*16
    const int srow   = w * 8 + (lane >> 3);          // 0..63
    const int schunk = (lane & 7) ^ (srow & 7);      // swizzled 16B chunk
    const int goff   = srow * DH + schunk * 8;       // element offset in 8KB tile
    char* const kdst = (char*)Ksm + w * 1024;
    char* const vdst = (char*)Vsm + w * 1024;

    float plsum[4] = {0.f, 0.f, 0.f, 0.f};
    f32x4 oacc[4] = {};

    for (int t = 0; t < 8; ++t) {
        gload16(Kh + t * 4096 + goff, kdst);
        gload16(Vh + t * 4096 + goff, vdst);
        __syncthreads();                 // drains vmcnt -> tiles ready

        // ---- QK^T: s[nf] covers kv cols nf*16+colw, q rows grp*4+r ----
        f32x4 s[4] = {};
        #pragma unroll
        for (int ks = 0; ks < 2; ++ks) {
            #pragma unroll
            for (int nf = 0; nf < 4; ++nf) {
                const int rowb = nf * 16 + colw;
                const short8 bk = *(const short8*)((char*)Ksm + rowb * 128 +
                                       ((((ks * 4 + grp) ^ (rowb & 7))) << 4));
                s[nf] = __builtin_amdgcn_mfma_f32_16x16x32_bf16(aq[ks], bk, s[nf], 0, 0, 0);
            }
        }
        // ---- p = exp(s), accumulate row sums, write P to per-wave LDS ----
        #pragma unroll
        for (int nf = 0; nf < 4; ++nf) {
            #pragma unroll
            for (int r = 0; r < 4; ++r) {
                const float p = __expf(s[nf][r]);
                plsum[r] += p;
                Psm[w][(grp * 4 + r) * 72 + nf * 16 + colw] = f2bf(p);
            }
        }
        // ---- PV: A = P (k=kv), B = V_lds (rows=d, k=kv) ----
        #pragma unroll
        for (int ks2 = 0; ks2 < 2; ++ks2) {
            const short8 ap = *(const short8*)&Psm[w][colw * 72 + ks2 * 32 + grp * 8];
            #pragma unroll
            for (int nf = 0; nf < 4; ++nf) {
                const int rowv = nf * 16 + colw;
                const short8 bv = *(const short8*)((char*)Vsm + rowv * 128 +
                                       ((((ks2 * 4 + grp) ^ (rowv & 7))) << 4));
                oacc[nf] = __builtin_amdgcn_mfma_f32_16x16x32_bf16(ap, bv, oacc[nf], 0, 0, 0);
            }
        }
        __syncthreads();                 // protect LDS tiles before restage
    }

    // single cross-lane reduce of the row sums (16-lane groups)
    float oinv[4];
    #pragma unroll
    for (int r = 0; r < 4; ++r) {
        float t = plsum[r];
        t += __shfl_xor(t, 1);
        t += __shfl_xor(t, 2);
        t += __shfl_xor(t, 4);
        t += __shfl_xor(t, 8);
        oinv[r] = 1.0f / t;
    }

    const int bt = bth >> 4, h = bth & 15;
    #pragma unroll
    for (int nf = 0; nf < 4; ++nf) {
        #pragma unroll
        for (int r = 0; r < 4; ++r) {
            const int i = bt * LSEQ + q0 + grp * 4 + r;
            const int c = h * 64 + nf * 16 + colw;
            Ob[(size_t)i * CD + c] = f2bf(oacc[nf][r] * oinv[r]);
        }
    }
}

// ---------------- Kernel 3: output projection + bias + residual ----------
__global__ __launch_bounds__(256, 2)
void proj_out_kernel(const unsigned short* __restrict__ Ob,
                     const unsigned short* __restrict__ wmb,
                     const float* __restrict__ bm,
                     const float* __restrict__ x, float* __restrict__ out)
{
    __shared__ __attribute__((aligned(16))) char lds[64 * 1024];

    // grid = 512 (64 m x 8 n); bijective XCD swizzle
    const int xcd = blockIdx.x & 7, wgl = blockIdx.x >> 3;   // wgl 0..63
    const int im  = xcd * 8 + (wgl >> 3);
    const int in  = wgl & 7;
    const int i0 = im * 128, j0 = in * 128;

    const int tid  = threadIdx.x;
    const int wv   = tid >> 6;
    const int lane = tid & 63;
    const int colw = lane & 15;
    const int grp  = lane >> 4;
    const int wr   = wv >> 1, wc = wv & 1;

    f32x4 acc[4][4] = {};
    gemm128_core(Ob, wmb, i0, j0, lds, acc);

    #pragma unroll
    for (int nf = 0; nf < 4; ++nf) {
        const int j = j0 + wc * 64 + nf * 16 + colw;
        const float bv = bm[j];
        #pragma unroll
        for (int mf = 0; mf < 4; ++mf) {
            #pragma unroll
            for (int r = 0; r < 4; ++r) {
                const int i = i0 + wr * 64 + mf * 16 + grp * 4 + r;
                out[(size_t)i * CD + j] = acc[mf][nf][r] + bv + x[(size_t)i * CD + j];
            }
        }
    }
}

extern "C" void kernel_launch(void* const* d_in, const int* in_sizes, int n_in,
                              void* d_out, int out_size, void* d_ws, size_t ws_size,
                              hipStream_t stream) {
    const float* x   = (const float*)d_in[0];
    const float* wq  = (const float*)d_in[1];
    const float* bq  = (const float*)d_in[2];
    const float* wkv = (const float*)d_in[3];
    const float* bkv = (const float*)d_in[4];
    const float* wm  = (const float*)d_in[5];
    const float* bm  = (const float*)d_in[6];
    float* out = (float*)d_out;

    // ws layout (64 MB, timeline-aliased):
    //  R0: xb (convert->proj_qkv), then Ob (attn->proj_out)
    //  R1: Qb (proj_qkv->attn), then wmb (cvt-after-attn->proj_out)
    //  R2: Kb   R3: Vtb
    // wqkvb lives in d_out (dead before proj_out writes it).
    const size_t SEG = (size_t)MROWS * CD;
    unsigned short* xb    = (unsigned short*)d_ws;
    unsigned short* Ob    = xb;
    unsigned short* Qb    = xb + SEG;
    unsigned short* wmb   = Qb;
    unsigned short* Kb    = Qb + SEG;
    unsigned short* Vtb   = Kb + SEG;
    unsigned short* wqkvb = (unsigned short*)d_out;

    cvt_kernel<<<2048, 256, 0, stream>>>(x,   xb,    (MROWS * CD) / 4);
    cvt_kernel<<<1024, 256, 0, stream>>>(wq,  wqkvb, (CD * CD) / 4);
    cvt_kernel<<<1024, 256, 0, stream>>>(wkv, wqkvb + (size_t)CD * CD, (2 * CD * CD) / 4);
    proj_qkv_kernel<<<1536, 256, 0, stream>>>(xb, wqkvb, bq, bkv, Qb, Kb, Vtb);
    attn_kernel<<<1024, 512, 0, stream>>>(Qb, Kb, Vtb, Ob);
    cvt_kernel<<<1024, 256, 0, stream>>>(wm, wmb, (CD * CD) / 4);
    proj_out_kernel<<<512, 256, 0, stream>>>(Ob, wmb, bm, x, out);
}